// Round 12
// baseline (2029.626 us; speedup 1.0000x reference)
//
#include <hip/hip_runtime.h>
#include <hip/hip_bf16.h>
#include <hip/hip_cooperative_groups.h>

namespace cg = cooperative_groups;

#define NTOK 4096
#define DEMB 1024
#define NH   8
#define DH   128
#define CWIN 256
#define QKVW 384
#define SCALE 0.08838834764831845f   // 1/sqrt(128)
#define QT 16
#define NCH 34                        // 16-key chunks covering the <=527-wide band

typedef __attribute__((ext_vector_type(8))) short short8;
typedef __attribute__((ext_vector_type(4))) float floatx4;

__device__ __forceinline__ short8 pack8(float4 a, float4 b) {
    union { __hip_bfloat16 h[8]; short8 v; } o;
    o.h[0] = __float2bfloat16(a.x); o.h[1] = __float2bfloat16(a.y);
    o.h[2] = __float2bfloat16(a.z); o.h[3] = __float2bfloat16(a.w);
    o.h[4] = __float2bfloat16(b.x); o.h[5] = __float2bfloat16(b.y);
    o.h[6] = __float2bfloat16(b.z); o.h[7] = __float2bfloat16(b.w);
    return o.v;
}

// ---------------- weight prep (once per call) ----------------
__global__ void pack_wqkv(const float* __restrict__ Wq, const float* __restrict__ Wk,
                          const float* __restrict__ Wvd, __hip_bfloat16* __restrict__ dst) {
    size_t base = ((size_t)blockIdx.x * 256 + threadIdx.x) * 8;
    int k = (int)(base & 1023);
    int rh = (int)(base >> 10);
    int h = rh / QKVW;
    int row = rh - h * QKVW;
    const float* srcs[3] = {Wq, Wk, Wvd};
    const float* s = srcs[row >> 7] + (((size_t)h * DH + (row & 127)) << 10) + k;
    *(short8*)(dst + base) = pack8(*(const float4*)s, *(const float4*)(s + 4));
}

__global__ void pack_wvu(const float* __restrict__ Wvu, __hip_bfloat16* __restrict__ dst) {
    size_t base = ((size_t)blockIdx.x * 256 + threadIdx.x) * 8;
    *(short8*)(dst + base) = pack8(*(const float4*)(Wvu + base), *(const float4*)(Wvu + base + 4));
}

// ---------------- next-head QKV tail (block's own 16 rows) -----------------
// A = Ebs (bf16 res rows, LDS). Q -> Qs (LDS, pre-scaled); K,V^T -> global.
__device__ __forceinline__ void qkv_tail(const __hip_bfloat16* __restrict__ Wqkv,
                                         __hip_bfloat16 (*Ebs)[DEMB + 8],
                                         __hip_bfloat16 (*Qs)[DH + 8],
                                         __hip_bfloat16* __restrict__ Kn,
                                         __hip_bfloat16* __restrict__ Vtn,
                                         int q0, int wave, int lane) {
    const int fr = lane & 15, kg = (lane >> 4) * 8, quad = lane >> 4;
    const int nt = (wave < 8) ? 2 : 1;        // tiles n = wave + 16t, n < 24
    floatx4 acc2[2] = {};
    #pragma unroll 8
    for (int kc = 0; kc < 32; kc++) {
        short8 a = *(const short8*)&Ebs[fr][kc * 32 + kg];
        #pragma unroll
        for (int t = 0; t < 2; t++) {
            if (t >= nt) break;
            int n = wave + 16 * t;
            acc2[t] = __builtin_amdgcn_mfma_f32_16x16x32_bf16(a,
                          *(const short8*)(Wqkv + (size_t)(n * 16 + fr) * DEMB + kc * 32 + kg),
                          acc2[t], 0, 0, 0);
        }
    }
    const int row0 = q0 + quad * 4;
    #pragma unroll
    for (int t = 0; t < 2; t++) {
        if (t >= nt) break;
        int n = wave + 16 * t;
        if (n < 8) {                   // Q -> LDS, pre-scaled
            int col = n * 16 + fr;
            #pragma unroll
            for (int rr = 0; rr < 4; rr++)
                Qs[quad * 4 + rr][col] = __float2bfloat16(acc2[t][rr] * SCALE);
        } else if (n < 16) {           // K -> global
            int col = (n - 8) * 16 + fr;
            #pragma unroll
            for (int rr = 0; rr < 4; rr++)
                Kn[(size_t)(row0 + rr) * DH + col] = __float2bfloat16(acc2[t][rr]);
        } else {                       // V^T -> global
            int d = (n - 16) * 16 + fr;
            union { __hip_bfloat16 h[4]; uint2 u; } p;
            #pragma unroll
            for (int rr = 0; rr < 4; rr++) p.h[rr] = __float2bfloat16(acc2[t][rr]);
            *(uint2*)(Vtn + (size_t)d * NTOK + row0) = p.u;
        }
    }
}

// ---------------- persistent mega kernel: all 8 heads ----------------------
// 256 blocks x 1024 threads, 1 block/CU (133 KB LDS). Block owns 16 token
// rows; e rows live in LDS fp32 for the whole computation. Heads separated
// by grid.sync() (cooperative launch); K/V^T ping-pong through global.
// OOB band-edge fragment reads land in the adjacent ws buffers (finite bf16),
// multiplied by p=0.
__global__ __launch_bounds__(1024) void mega(const float* __restrict__ x,
                                             const __hip_bfloat16* __restrict__ wqkv,
                                             const __hip_bfloat16* __restrict__ wvu,
                                             __hip_bfloat16* __restrict__ K0,
                                             __hip_bfloat16* __restrict__ Vt0,
                                             __hip_bfloat16* __restrict__ K1,
                                             __hip_bfloat16* __restrict__ Vt1,
                                             float* __restrict__ out_final) {
    cg::grid_group grid = cg::this_grid();
    // XCD swizzle: 32 token-contiguous blocks per XCD (band K/V L2 locality).
    const int vb = ((blockIdx.x & 7) << 5) | (blockIdx.x >> 3);
    const int q0 = vb * QT;
    const int tid = threadIdx.x;
    const int wave = tid >> 6, lane = tid & 63;
    const int fr = lane & 15, kg = (lane >> 4) * 8;
    const int quad = lane >> 4;

    __hip_bfloat16* Kg[2]  = {K0, K1};
    __hip_bfloat16* Vtg[2] = {Vt0, Vt1};

    __shared__ alignas(16) float eL[QT][DEMB + 4];             // 65792 B: resident e rows
    __shared__ alignas(16) __hip_bfloat16 Ebs[QT][DEMB + 8];   // 33024 B: bf16 res rows
    __shared__ alignas(16) __hip_bfloat16 Qs[QT][DH + 8];      //  4352 B: Q tile / u rows
    __shared__ alignas(16) char Ubuf[33024];                   // softmax bufs / Dbs overlay

    auto Pb     = (__hip_bfloat16 (*)[NCH * 16 + 8]) Ubuf;     // 16 x 552  (17664 B)
    auto Opart  = (float (*)[64][4])(Ubuf + 17664);            // 8x64x4    ( 8192 B)
    auto statsA = (float (*)[16])(Ubuf + 17664 + 8192);        // 16 x 16   ( 1024 B)
    auto statsB = (float (*)[16])(Ubuf + 17664 + 8192 + 1024);
    auto Dbs    = (__hip_bfloat16 (*)[DEMB + 4])Ubuf;          // 16 x 1028 (32896 B)

    // ---- init: load x rows -> eL + Ebs (row-per-wave, coalesced) ----------
    {
        const size_t rowbase = (size_t)(q0 + wave) * DEMB;
        #pragma unroll
        for (int j = 0; j < 4; j++) {
            int c4 = (j * 64 + lane) * 4;
            float4 v = *(const float4*)(x + rowbase + c4);
            *(float4*)&eL[wave][c4] = v;
            union { __hip_bfloat16 h[4]; uint2 u; } p;
            p.h[0] = __float2bfloat16(v.x); p.h[1] = __float2bfloat16(v.y);
            p.h[2] = __float2bfloat16(v.z); p.h[3] = __float2bfloat16(v.w);
            *(uint2*)&Ebs[wave][c4] = p.u;
        }
    }
    __syncthreads();

    // ---- head-0 QKV -------------------------------------------------------
    qkv_tail(wqkv, Ebs, Qs, Kg[0], Vtg[0], q0, wave, lane);
    __threadfence();
    grid.sync();
    __threadfence();

    const int kstart = max(q0 - CWIN, 0);
    const int kend   = min(q0 + QT - 1 + CWIN + 1, NTOK);
    const int nch = (wave < 2) ? 3 : 2;       // score chunks ch = wave + 16t, ch < 34

    for (int h = 0; h < NH; h++) {
        const int cur = h & 1;
        const bool last = (h == NH - 1);
        const __hip_bfloat16* Kb  = Kg[cur];
        const __hip_bfloat16* Vtb = Vtg[cur];

        short8 af[4];
        #pragma unroll
        for (int kc = 0; kc < 4; kc++) af[kc] = *(const short8*)&Qs[fr][kc * 32 + kg];

        // ---- scores: wave's 2-3 chunks, K fragments from global/L2 --------
        floatx4 sreg[3];
        #pragma unroll
        for (int t = 0; t < 3; t++) {
            if (t >= nch) break;
            int ch = wave + 16 * t;
            const __hip_bfloat16* krow = Kb + (size_t)(kstart + ch * 16 + fr) * DH;
            floatx4 s = {};
            #pragma unroll
            for (int kc = 0; kc < 4; kc++)
                s = __builtin_amdgcn_mfma_f32_16x16x32_bf16(af[kc],
                        *(const short8*)(krow + kc * 32 + kg), s, 0, 0, 0);
            sreg[t] = s;
        }

        // ---- band mask + per-row max --------------------------------------
        float pmax[4] = {-1e30f, -1e30f, -1e30f, -1e30f};
        #pragma unroll
        for (int t = 0; t < 3; t++) {
            if (t >= nch) break;
            int tcol = kstart + (wave + 16 * t) * 16 + fr;
            #pragma unroll
            for (int r = 0; r < 4; r++) {
                int qg = q0 + quad * 4 + r;
                bool ok = (tcol < kend) && (tcol >= qg - CWIN) && (tcol < qg + CWIN);
                float v = ok ? sreg[t][r] : -1e30f;
                sreg[t][r] = v;
                pmax[r] = fmaxf(pmax[r], v);
            }
        }
        #pragma unroll
        for (int mm = 1; mm <= 8; mm <<= 1)
            #pragma unroll
            for (int r = 0; r < 4; r++) pmax[r] = fmaxf(pmax[r], __shfl_xor(pmax[r], mm, 64));
        if (fr == 0)
            #pragma unroll
            for (int r = 0; r < 4; r++) statsA[quad * 4 + r][wave] = pmax[r];
        __syncthreads();

        float M[4];
        #pragma unroll
        for (int r = 0; r < 4; r++) {
            int row = quad * 4 + r;
            float m = statsA[row][0];
            #pragma unroll
            for (int w = 1; w < 16; w++) m = fmaxf(m, statsA[row][w]);
            M[r] = m;
        }

        // ---- exp -> Pb (A-layout), row sums -------------------------------
        float psum[4] = {};
        #pragma unroll
        for (int t = 0; t < 3; t++) {
            if (t >= nch) break;
            int colb = (wave + 16 * t) * 16 + fr;
            #pragma unroll
            for (int r = 0; r < 4; r++) {
                float p = __expf(sreg[t][r] - M[r]);
                psum[r] += p;
                Pb[quad * 4 + r][colb] = __float2bfloat16(p);
            }
        }
        #pragma unroll
        for (int mm = 1; mm <= 8; mm <<= 1)
            #pragma unroll
            for (int r = 0; r < 4; r++) psum[r] += __shfl_xor(psum[r], mm, 64);
        if (fr == 0)
            #pragma unroll
            for (int r = 0; r < 4; r++) statsB[quad * 4 + r][wave] = psum[r];
        __syncthreads();

        // ---- PV split in two kc-halves: wave = half*8 + dim-group ---------
        const int g = wave & 7, half = wave >> 3;
        {
            floatx4 Of = {};
            const int kc0 = half ? 9 : 0, kc1 = half ? 17 : 9;
            for (int kc = kc0; kc < kc1; kc++) {
                short8 pf = *(const short8*)&Pb[fr][kc * 32 + kg];
                const __hip_bfloat16* vrow = Vtb + (size_t)(g * 16 + fr) * NTOK
                                           + kstart + kc * 32 + kg;
                Of = __builtin_amdgcn_mfma_f32_16x16x32_bf16(pf, *(const short8*)vrow,
                                                             Of, 0, 0, 0);
            }
            if (half) *(float4*)&Opart[g][lane][0] = *(float4*)&Of;
            __syncthreads();
            if (!half) {
                float4 o2 = *(const float4*)&Opart[g][lane][0];
                float linv[4];
                #pragma unroll
                for (int r = 0; r < 4; r++) {
                    int row = quad * 4 + r;
                    float s = 0.f;
                    #pragma unroll
                    for (int w = 0; w < 16; w++) s += statsB[row][w];
                    linv[r] = 1.0f / s;
                }
                int col = g * 16 + fr;
                Qs[quad * 4 + 0][col] = __float2bfloat16((Of[0] + o2.x) * linv[0]);
                Qs[quad * 4 + 1][col] = __float2bfloat16((Of[1] + o2.y) * linv[1]);
                Qs[quad * 4 + 2][col] = __float2bfloat16((Of[2] + o2.z) * linv[2]);
                Qs[quad * 4 + 3][col] = __float2bfloat16((Of[3] + o2.w) * linv[3]);
            }
        }
        __syncthreads();                   // u ready; Pb/Opart/stats now dead
        short8 af2[4];
        #pragma unroll
        for (int kc = 0; kc < 4; kc++) af2[kc] = *(const short8*)&Qs[fr][kc * 32 + kg];

        // ---- out-proj: wave owns cols [64w,64w+64); delta -> Dbs ----------
        {
            floatx4 accd[4] = {};
            #pragma unroll
            for (int n0 = 0; n0 < 4; n0++) {
                const __hip_bfloat16* wrow = wvu + (size_t)h * DEMB * DH
                                           + ((size_t)(wave * 64 + n0 * 16 + fr) << 7);
                #pragma unroll
                for (int kc = 0; kc < 4; kc++)
                    accd[n0] = __builtin_amdgcn_mfma_f32_16x16x32_bf16(af2[kc],
                                   *(const short8*)(wrow + kc * 32 + kg), accd[n0], 0, 0, 0);
            }
            #pragma unroll
            for (int n0 = 0; n0 < 4; n0++) {
                int col = wave * 64 + n0 * 16 + fr;
                #pragma unroll
                for (int r = 0; r < 4; r++)
                    Dbs[quad * 4 + r][col] = __float2bfloat16(accd[n0][r]);
            }
        }
        __syncthreads();                   // Dbs complete

        // ---- row-per-wave norm, all from LDS ------------------------------
        {
            float4 ev[4];
            float od[16];
            float s1 = 0.f, s2 = 0.f;
            #pragma unroll
            for (int j = 0; j < 4; j++) {
                int c4 = (j * 64 + lane) * 4;
                ev[j] = *(const float4*)&eL[wave][c4];
                union { uint2 u; __hip_bfloat16 h[4]; } dp;
                dp.u = *(const uint2*)&Dbs[wave][c4];
                od[j * 4 + 0] = ev[j].x + __bfloat162float(dp.h[0]);
                od[j * 4 + 1] = ev[j].y + __bfloat162float(dp.h[1]);
                od[j * 4 + 2] = ev[j].z + __bfloat162float(dp.h[2]);
                od[j * 4 + 3] = ev[j].w + __bfloat162float(dp.h[3]);
                #pragma unroll
                for (int c = 0; c < 4; c++) {
                    s1 += od[j * 4 + c];
                    s2 += od[j * 4 + c] * od[j * 4 + c];
                }
            }
            #pragma unroll
            for (int mm = 1; mm <= 32; mm <<= 1) {
                s1 += __shfl_xor(s1, mm, 64);
                s2 += __shfl_xor(s2, mm, 64);
            }
            float m0 = s1 * (1.0f / DEMB);
            float iv = 1.0f / m0;
            float m  = m0 * iv;                    // mean(out/m0) ~ 1
            float st = s1 * iv;
            float var = (s2 * iv * iv - st * st * (1.0f / DEMB)) * (1.0f / (DEMB - 1));
            float isd = rsqrtf(var);

            const size_t rowbase = (size_t)(q0 + wave) * DEMB;
            #pragma unroll
            for (int j = 0; j < 4; j++) {
                int c4 = (j * 64 + lane) * 4;
                float4 res;
                res.x = ev[j].x + (od[j * 4 + 0] * iv - m) * isd + m;
                res.y = ev[j].y + (od[j * 4 + 1] * iv - m) * isd + m;
                res.z = ev[j].z + (od[j * 4 + 2] * iv - m) * isd + m;
                res.w = ev[j].w + (od[j * 4 + 3] * iv - m) * isd + m;
                if (last) {
                    *(float4*)(out_final + rowbase + c4) =
                        make_float4(res.x * 0.125f, res.y * 0.125f,
                                    res.z * 0.125f, res.w * 0.125f);
                } else {
                    *(float4*)&eL[wave][c4] = res;
                    union { __hip_bfloat16 h[4]; uint2 u; } p;
                    p.h[0] = __float2bfloat16(res.x); p.h[1] = __float2bfloat16(res.y);
                    p.h[2] = __float2bfloat16(res.z); p.h[3] = __float2bfloat16(res.w);
                    *(uint2*)&Ebs[wave][c4] = p.u;
                }
            }
        }

        // ---- next-head QKV + grid barrier ---------------------------------
        if (!last) {
            __syncthreads();               // Ebs complete
            qkv_tail(wqkv + (size_t)(h + 1) * QKVW * DEMB, Ebs, Qs,
                     Kg[1 - cur], Vtg[1 - cur], q0, wave, lane);
            __threadfence();
            grid.sync();
            __threadfence();
        }
    }
}

extern "C" void kernel_launch(void* const* d_in, const int* in_sizes, int n_in,
                              void* d_out, int out_size, void* d_ws, size_t ws_size,
                              hipStream_t stream) {
    const float* x   = (const float*)d_in[0];
    const float* Wq  = (const float*)d_in[1];
    const float* Wk  = (const float*)d_in[2];
    const float* Wvd = (const float*)d_in[3];
    const float* Wvu = (const float*)d_in[4];

    char* ws = (char*)d_ws;
    // Contiguous K/Vt buffers (1 MB each): OOB band-edge reads stay in ws.
    __hip_bfloat16* K0    = (__hip_bfloat16*)(ws + (24u << 20));
    __hip_bfloat16* V0    = (__hip_bfloat16*)(ws + (25u << 20));
    __hip_bfloat16* K1    = (__hip_bfloat16*)(ws + (26u << 20));
    __hip_bfloat16* V1    = (__hip_bfloat16*)(ws + (27u << 20));
    __hip_bfloat16* wqkvb = (__hip_bfloat16*)(ws + (28u << 20));        // 6 MB
    __hip_bfloat16* wvub  = (__hip_bfloat16*)(ws + (34u << 20));        // 2 MB -> 36 MB

    pack_wqkv<<<NH * QKVW * DEMB / 8 / 256, 256, 0, stream>>>(Wq, Wk, Wvd, wqkvb);
    pack_wvu<<<NH * DEMB * DH / 8 / 256, 256, 0, stream>>>(Wvu, wvub);

    float* outp = (float*)d_out;
    void* args[] = {(void*)&x, (void*)&wqkvb, (void*)&wvub,
                    (void*)&K0, (void*)&V0, (void*)&K1, (void*)&V1, (void*)&outp};
    hipLaunchCooperativeKernel((const void*)mega, dim3(NTOK / QT), dim3(1024),
                               args, 0, stream);
}

// Round 13
// 1345.432 us; speedup vs baseline: 1.5085x; 1.5085x over previous
//
#include <hip/hip_runtime.h>
#include <hip/hip_bf16.h>

#define NTOK 4096
#define DEMB 1024
#define NH   8
#define DH   128
#define CWIN 256
#define QKVW 384
#define SCALE 0.08838834764831845f   // 1/sqrt(128)
#define QT 16
#define NCH 34                        // 16-key chunks covering the <=527-wide band
#define NB  (NTOK / QT)               // 256 token-blocks

typedef __attribute__((ext_vector_type(8))) short short8;
typedef __attribute__((ext_vector_type(4))) float floatx4;

__device__ __forceinline__ short8 pack8(float4 a, float4 b) {
    union { __hip_bfloat16 h[8]; short8 v; } o;
    o.h[0] = __float2bfloat16(a.x); o.h[1] = __float2bfloat16(a.y);
    o.h[2] = __float2bfloat16(a.z); o.h[3] = __float2bfloat16(a.w);
    o.h[4] = __float2bfloat16(b.x); o.h[5] = __float2bfloat16(b.y);
    o.h[6] = __float2bfloat16(b.z); o.h[7] = __float2bfloat16(b.w);
    return o.v;
}

// ---------------- weight prep + flag init (once per call) ----------------
__global__ void pack_wqkv(const float* __restrict__ Wq, const float* __restrict__ Wk,
                          const float* __restrict__ Wvd, __hip_bfloat16* __restrict__ dst) {
    size_t base = ((size_t)blockIdx.x * 256 + threadIdx.x) * 8;
    int k = (int)(base & 1023);
    int rh = (int)(base >> 10);
    int h = rh / QKVW;
    int row = rh - h * QKVW;
    const float* srcs[3] = {Wq, Wk, Wvd};
    const float* s = srcs[row >> 7] + (((size_t)h * DH + (row & 127)) << 10) + k;
    *(short8*)(dst + base) = pack8(*(const float4*)s, *(const float4*)(s + 4));
}

__global__ void pack_wvu(const float* __restrict__ Wvu, __hip_bfloat16* __restrict__ dst) {
    size_t base = ((size_t)blockIdx.x * 256 + threadIdx.x) * 8;
    *(short8*)(dst + base) = pack8(*(const float4*)(Wvu + base), *(const float4*)(Wvu + base + 4));
}

__global__ void init_flags(int* __restrict__ cnt) {
    cnt[threadIdx.x] = 0;             // ws is re-poisoned 0xAA every launch
}

// ---------------- next-head QKV tail (block's own 16 rows) -----------------
__device__ __forceinline__ void qkv_tail(const __hip_bfloat16* __restrict__ Wqkv,
                                         __hip_bfloat16 (*Ebs)[DEMB + 8],
                                         __hip_bfloat16 (*Qs)[DH + 8],
                                         __hip_bfloat16* __restrict__ Kn,
                                         __hip_bfloat16* __restrict__ Vtn,
                                         int q0, int wave, int lane) {
    const int fr = lane & 15, kg = (lane >> 4) * 8, quad = lane >> 4;
    const int nt = (wave < 8) ? 2 : 1;        // tiles n = wave + 16t, n < 24
    floatx4 acc2[2] = {};
    #pragma unroll 8
    for (int kc = 0; kc < 32; kc++) {
        short8 a = *(const short8*)&Ebs[fr][kc * 32 + kg];
        #pragma unroll
        for (int t = 0; t < 2; t++) {
            if (t >= nt) break;
            int n = wave + 16 * t;
            acc2[t] = __builtin_amdgcn_mfma_f32_16x16x32_bf16(a,
                          *(const short8*)(Wqkv + (size_t)(n * 16 + fr) * DEMB + kc * 32 + kg),
                          acc2[t], 0, 0, 0);
        }
    }
    const int row0 = q0 + quad * 4;
    #pragma unroll
    for (int t = 0; t < 2; t++) {
        if (t >= nt) break;
        int n = wave + 16 * t;
        if (n < 8) {                   // Q -> LDS, pre-scaled
            int col = n * 16 + fr;
            #pragma unroll
            for (int rr = 0; rr < 4; rr++)
                Qs[quad * 4 + rr][col] = __float2bfloat16(acc2[t][rr] * SCALE);
        } else if (n < 16) {           // K -> global
            int col = (n - 8) * 16 + fr;
            #pragma unroll
            for (int rr = 0; rr < 4; rr++)
                Kn[(size_t)(row0 + rr) * DH + col] = __float2bfloat16(acc2[t][rr]);
        } else {                       // V^T -> global
            int d = (n - 16) * 16 + fr;
            union { __hip_bfloat16 h[4]; uint2 u; } p;
            #pragma unroll
            for (int rr = 0; rr < 4; rr++) p.h[rr] = __float2bfloat16(acc2[t][rr]);
            *(uint2*)(Vtn + (size_t)d * NTOK + row0) = p.u;
        }
    }
}

// ---------------- persistent mega kernel: all 8 heads, flag-synced ---------
// 256 blocks x 1024 threads, 1 block/CU (133 KB LDS -> all blocks resident;
// grid == CU count). Block owns 16 token rows; e lives in LDS throughout.
// Cross-block dependency is band-local: task(h,vb) reads K/V rows of
// vb-16..vb+16 only, so sync is a per-block monotone counter published with
// device-scope release and spin-read with acquire (guide G16). Dependencies
// are acyclic; all blocks resident -> no deadlock. Reads of not-yet-
// published rows beyond kend are band-masked to p=0 (value discarded).
__global__ __launch_bounds__(1024) void mega(const float* __restrict__ x,
                                             const __hip_bfloat16* __restrict__ wqkv,
                                             const __hip_bfloat16* __restrict__ wvu,
                                             __hip_bfloat16* __restrict__ K0,
                                             __hip_bfloat16* __restrict__ Vt0,
                                             __hip_bfloat16* __restrict__ K1,
                                             __hip_bfloat16* __restrict__ Vt1,
                                             int* __restrict__ cnt,
                                             float* __restrict__ out_final) {
    // XCD swizzle: 32 token-contiguous blocks per XCD (neighbors share L2).
    const int vb = ((blockIdx.x & 7) << 5) | (blockIdx.x >> 3);
    const int q0 = vb * QT;
    const int tid = threadIdx.x;
    const int wave = tid >> 6, lane = tid & 63;
    const int fr = lane & 15, kg = (lane >> 4) * 8;
    const int quad = lane >> 4;

    __hip_bfloat16* Kg[2]  = {K0, K1};
    __hip_bfloat16* Vtg[2] = {Vt0, Vt1};

    __shared__ alignas(16) float eL[QT][DEMB + 4];             // 65792 B
    __shared__ alignas(16) __hip_bfloat16 Ebs[QT][DEMB + 8];   // 33024 B
    __shared__ alignas(16) __hip_bfloat16 Qs[QT][DH + 8];      //  4352 B
    __shared__ alignas(16) char Ubuf[33024];

    auto Pb     = (__hip_bfloat16 (*)[NCH * 16 + 8]) Ubuf;     // 16 x 552
    auto Opart  = (float (*)[64][4])(Ubuf + 17664);            // 8x64x4
    auto statsA = (float (*)[16])(Ubuf + 17664 + 8192);        // 16x16
    auto statsB = (float (*)[16])(Ubuf + 17664 + 8192 + 1024);
    auto Dbs    = (__hip_bfloat16 (*)[DEMB + 4])Ubuf;          // 16 x 1028

    // ---- init: load x rows -> eL + Ebs ------------------------------------
    {
        const size_t rowbase = (size_t)(q0 + wave) * DEMB;
        #pragma unroll
        for (int j = 0; j < 4; j++) {
            int c4 = (j * 64 + lane) * 4;
            float4 v = *(const float4*)(x + rowbase + c4);
            *(float4*)&eL[wave][c4] = v;
            union { __hip_bfloat16 h[4]; uint2 u; } p;
            p.h[0] = __float2bfloat16(v.x); p.h[1] = __float2bfloat16(v.y);
            p.h[2] = __float2bfloat16(v.z); p.h[3] = __float2bfloat16(v.w);
            *(uint2*)&Ebs[wave][c4] = p.u;
        }
    }
    __syncthreads();

    // ---- head-0 QKV + publish cnt=1 ---------------------------------------
    qkv_tail(wqkv, Ebs, Qs, Kg[0], Vtg[0], q0, wave, lane);
    __threadfence();
    __syncthreads();
    if (tid == 0)
        __hip_atomic_store(&cnt[vb], 1, __ATOMIC_RELEASE, __HIP_MEMORY_SCOPE_AGENT);

    const int kstart = max(q0 - CWIN, 0);
    const int kend   = min(q0 + QT - 1 + CWIN + 1, NTOK);
    const int nch = (wave < 2) ? 3 : 2;       // score chunks ch = wave + 16t, ch < 34

    for (int h = 0; h < NH; h++) {
        const int cur = h & 1;
        const bool last = (h == NH - 1);
        const __hip_bfloat16* Kb  = Kg[cur];
        const __hip_bfloat16* Vtb = Vtg[cur];

        // ---- wait for neighbors' K_h/V_h (cnt >= h+1) ---------------------
        if (tid < 33) {
            int nb = min(max(vb - 16 + tid, 0), NB - 1);
            while (__hip_atomic_load(&cnt[nb], __ATOMIC_ACQUIRE,
                                     __HIP_MEMORY_SCOPE_AGENT) < h + 1)
                __builtin_amdgcn_s_sleep(2);
        }
        __syncthreads();

        short8 af[4];
        #pragma unroll
        for (int kc = 0; kc < 4; kc++) af[kc] = *(const short8*)&Qs[fr][kc * 32 + kg];

        // ---- scores -------------------------------------------------------
        floatx4 sreg[3];
        #pragma unroll
        for (int t = 0; t < 3; t++) {
            if (t >= nch) break;
            int ch = wave + 16 * t;
            const __hip_bfloat16* krow = Kb + (size_t)(kstart + ch * 16 + fr) * DH;
            floatx4 s = {};
            #pragma unroll
            for (int kc = 0; kc < 4; kc++)
                s = __builtin_amdgcn_mfma_f32_16x16x32_bf16(af[kc],
                        *(const short8*)(krow + kc * 32 + kg), s, 0, 0, 0);
            sreg[t] = s;
        }

        // ---- band mask + per-row max --------------------------------------
        float pmax[4] = {-1e30f, -1e30f, -1e30f, -1e30f};
        #pragma unroll
        for (int t = 0; t < 3; t++) {
            if (t >= nch) break;
            int tcol = kstart + (wave + 16 * t) * 16 + fr;
            #pragma unroll
            for (int r = 0; r < 4; r++) {
                int qg = q0 + quad * 4 + r;
                bool ok = (tcol < kend) && (tcol >= qg - CWIN) && (tcol < qg + CWIN);
                float v = ok ? sreg[t][r] : -1e30f;
                sreg[t][r] = v;
                pmax[r] = fmaxf(pmax[r], v);
            }
        }
        #pragma unroll
        for (int mm = 1; mm <= 8; mm <<= 1)
            #pragma unroll
            for (int r = 0; r < 4; r++) pmax[r] = fmaxf(pmax[r], __shfl_xor(pmax[r], mm, 64));
        if (fr == 0)
            #pragma unroll
            for (int r = 0; r < 4; r++) statsA[quad * 4 + r][wave] = pmax[r];
        __syncthreads();

        float M[4];
        #pragma unroll
        for (int r = 0; r < 4; r++) {
            int row = quad * 4 + r;
            float m = statsA[row][0];
            #pragma unroll
            for (int w = 1; w < 16; w++) m = fmaxf(m, statsA[row][w]);
            M[r] = m;
        }

        // ---- exp -> Pb (A-layout), row sums -------------------------------
        float psum[4] = {};
        #pragma unroll
        for (int t = 0; t < 3; t++) {
            if (t >= nch) break;
            int colb = (wave + 16 * t) * 16 + fr;
            #pragma unroll
            for (int r = 0; r < 4; r++) {
                float p = __expf(sreg[t][r] - M[r]);
                psum[r] += p;
                Pb[quad * 4 + r][colb] = __float2bfloat16(p);
            }
        }
        #pragma unroll
        for (int mm = 1; mm <= 8; mm <<= 1)
            #pragma unroll
            for (int r = 0; r < 4; r++) psum[r] += __shfl_xor(psum[r], mm, 64);
        if (fr == 0)
            #pragma unroll
            for (int r = 0; r < 4; r++) statsB[quad * 4 + r][wave] = psum[r];
        __syncthreads();

        // ---- PV split in two kc-halves ------------------------------------
        const int g = wave & 7, half = wave >> 3;
        {
            floatx4 Of = {};
            const int kc0 = half ? 9 : 0, kc1 = half ? 17 : 9;
            for (int kc = kc0; kc < kc1; kc++) {
                short8 pf = *(const short8*)&Pb[fr][kc * 32 + kg];
                const __hip_bfloat16* vrow = Vtb + (size_t)(g * 16 + fr) * NTOK
                                           + kstart + kc * 32 + kg;
                Of = __builtin_amdgcn_mfma_f32_16x16x32_bf16(pf, *(const short8*)vrow,
                                                             Of, 0, 0, 0);
            }
            if (half) *(float4*)&Opart[g][lane][0] = *(float4*)&Of;
            __syncthreads();
            if (!half) {
                float4 o2 = *(const float4*)&Opart[g][lane][0];
                float linv[4];
                #pragma unroll
                for (int r = 0; r < 4; r++) {
                    int row = quad * 4 + r;
                    float s = 0.f;
                    #pragma unroll
                    for (int w = 0; w < 16; w++) s += statsB[row][w];
                    linv[r] = 1.0f / s;
                }
                int col = g * 16 + fr;
                Qs[quad * 4 + 0][col] = __float2bfloat16((Of[0] + o2.x) * linv[0]);
                Qs[quad * 4 + 1][col] = __float2bfloat16((Of[1] + o2.y) * linv[1]);
                Qs[quad * 4 + 2][col] = __float2bfloat16((Of[2] + o2.z) * linv[2]);
                Qs[quad * 4 + 3][col] = __float2bfloat16((Of[3] + o2.w) * linv[3]);
            }
        }
        __syncthreads();                   // u ready; Pb/Opart/stats now dead
        short8 af2[4];
        #pragma unroll
        for (int kc = 0; kc < 4; kc++) af2[kc] = *(const short8*)&Qs[fr][kc * 32 + kg];

        // ---- out-proj: delta -> Dbs ---------------------------------------
        {
            floatx4 accd[4] = {};
            #pragma unroll
            for (int n0 = 0; n0 < 4; n0++) {
                const __hip_bfloat16* wrow = wvu + (size_t)h * DEMB * DH
                                           + ((size_t)(wave * 64 + n0 * 16 + fr) << 7);
                #pragma unroll
                for (int kc = 0; kc < 4; kc++)
                    accd[n0] = __builtin_amdgcn_mfma_f32_16x16x32_bf16(af2[kc],
                                   *(const short8*)(wrow + kc * 32 + kg), accd[n0], 0, 0, 0);
            }
            #pragma unroll
            for (int n0 = 0; n0 < 4; n0++) {
                int col = wave * 64 + n0 * 16 + fr;
                #pragma unroll
                for (int r = 0; r < 4; r++)
                    Dbs[quad * 4 + r][col] = __float2bfloat16(accd[n0][r]);
            }
        }
        __syncthreads();                   // Dbs complete

        // ---- row-per-wave norm, all from LDS ------------------------------
        {
            float4 ev[4];
            float od[16];
            float s1 = 0.f, s2 = 0.f;
            #pragma unroll
            for (int j = 0; j < 4; j++) {
                int c4 = (j * 64 + lane) * 4;
                ev[j] = *(const float4*)&eL[wave][c4];
                union { uint2 u; __hip_bfloat16 h[4]; } dp;
                dp.u = *(const uint2*)&Dbs[wave][c4];
                od[j * 4 + 0] = ev[j].x + __bfloat162float(dp.h[0]);
                od[j * 4 + 1] = ev[j].y + __bfloat162float(dp.h[1]);
                od[j * 4 + 2] = ev[j].z + __bfloat162float(dp.h[2]);
                od[j * 4 + 3] = ev[j].w + __bfloat162float(dp.h[3]);
                #pragma unroll
                for (int c = 0; c < 4; c++) {
                    s1 += od[j * 4 + c];
                    s2 += od[j * 4 + c] * od[j * 4 + c];
                }
            }
            #pragma unroll
            for (int mm = 1; mm <= 32; mm <<= 1) {
                s1 += __shfl_xor(s1, mm, 64);
                s2 += __shfl_xor(s2, mm, 64);
            }
            float m0 = s1 * (1.0f / DEMB);
            float iv = 1.0f / m0;
            float m  = m0 * iv;                    // mean(out/m0) ~ 1
            float st = s1 * iv;
            float var = (s2 * iv * iv - st * st * (1.0f / DEMB)) * (1.0f / (DEMB - 1));
            float isd = rsqrtf(var);

            const size_t rowbase = (size_t)(q0 + wave) * DEMB;
            #pragma unroll
            for (int j = 0; j < 4; j++) {
                int c4 = (j * 64 + lane) * 4;
                float4 res;
                res.x = ev[j].x + (od[j * 4 + 0] * iv - m) * isd + m;
                res.y = ev[j].y + (od[j * 4 + 1] * iv - m) * isd + m;
                res.z = ev[j].z + (od[j * 4 + 2] * iv - m) * isd + m;
                res.w = ev[j].w + (od[j * 4 + 3] * iv - m) * isd + m;
                if (last) {
                    *(float4*)(out_final + rowbase + c4) =
                        make_float4(res.x * 0.125f, res.y * 0.125f,
                                    res.z * 0.125f, res.w * 0.125f);
                } else {
                    *(float4*)&eL[wave][c4] = res;
                    union { __hip_bfloat16 h[4]; uint2 u; } p;
                    p.h[0] = __float2bfloat16(res.x); p.h[1] = __float2bfloat16(res.y);
                    p.h[2] = __float2bfloat16(res.z); p.h[3] = __float2bfloat16(res.w);
                    *(uint2*)&Ebs[wave][c4] = p.u;
                }
            }
        }

        // ---- next-head QKV + publish --------------------------------------
        if (!last) {
            __syncthreads();               // Ebs complete
            qkv_tail(wqkv + (size_t)(h + 1) * QKVW * DEMB, Ebs, Qs,
                     Kg[1 - cur], Vtg[1 - cur], q0, wave, lane);
            __threadfence();
            __syncthreads();
            if (tid == 0)
                __hip_atomic_store(&cnt[vb], h + 2, __ATOMIC_RELEASE,
                                   __HIP_MEMORY_SCOPE_AGENT);
        }
    }
}

extern "C" void kernel_launch(void* const* d_in, const int* in_sizes, int n_in,
                              void* d_out, int out_size, void* d_ws, size_t ws_size,
                              hipStream_t stream) {
    const float* x   = (const float*)d_in[0];
    const float* Wq  = (const float*)d_in[1];
    const float* Wk  = (const float*)d_in[2];
    const float* Wvd = (const float*)d_in[3];
    const float* Wvu = (const float*)d_in[4];

    char* ws = (char*)d_ws;
    int* cnt              = (int*)(ws + (23u << 20));
    __hip_bfloat16* K0    = (__hip_bfloat16*)(ws + (24u << 20));
    __hip_bfloat16* V0    = (__hip_bfloat16*)(ws + (25u << 20));
    __hip_bfloat16* K1    = (__hip_bfloat16*)(ws + (26u << 20));
    __hip_bfloat16* V1    = (__hip_bfloat16*)(ws + (27u << 20));
    __hip_bfloat16* wqkvb = (__hip_bfloat16*)(ws + (28u << 20));        // 6 MB
    __hip_bfloat16* wvub  = (__hip_bfloat16*)(ws + (34u << 20));        // 2 MB -> 36 MB

    pack_wqkv<<<NH * QKVW * DEMB / 8 / 256, 256, 0, stream>>>(Wq, Wk, Wvd, wqkvb);
    pack_wvu<<<NH * DEMB * DH / 8 / 256, 256, 0, stream>>>(Wvu, wvub);
    init_flags<<<1, NB, 0, stream>>>(cnt);

    mega<<<NB, 1024, 0, stream>>>(x, wqkvb, wvub, K0, V0, K1, V1, cnt, (float*)d_out);
}